// Round 14
// baseline (414.121 us; speedup 1.0000x reference)
//
#include <hip/hip_runtime.h>
#include <math.h>

// ---------------------------------------------------------------------------
// PAE pipeline on MI355X. Round 14:
//   k_fused replaces k_q + k_prefix_ln: per (b,o) block computes
//   D'[m][s'] = sum_c w1[o,c,m] x[b,c,s'] via MFMA into LDS (117KB, stride
//   242), exploits Q[m][s] = D'[m][(s+m)%240] for an in-place anti-diagonal
//   prefix, then LN/tanh gather (fixed-column algebra) -> bf16 h3 to a
//   dedicated global buffer (2-chunk staged coalesced dump). Eliminates
//   ~110 MB of Q traffic and a launch.
//   k_enc2: fc/bm epilogues parallelized (16/32 lanes per output + shfl_xor);
//   reads h3 from the new buffer. Rest identical to round 13 (verified).
// ---------------------------------------------------------------------------

#define INCH   72
#define TLEN   121
#define FULL   240
#define INTER  24
#define EMB    8
#define LP     360
#define NWIN   3840

typedef __attribute__((ext_vector_type(8)))  short s16x8;
typedef __attribute__((ext_vector_type(4)))  float f32x4;

__device__ __forceinline__ unsigned short f2bf(float f) {
    unsigned u = __float_as_uint(f);
    unsigned r = ((u >> 16) & 1u) + 0x7FFFu;
    return (unsigned short)((u + r) >> 16);
}

// ---------------------------------------------------------------------------
// k_prep_all: w2f | w3f | w1fB in one launch.
// w1fB[((o*8+mt)*3+ch)*512 + ln*8 + j]: A-frag, m=mt*16+(ln&15),
// c=ch*32+(ln>>4)*8+j, zero for c>=72 or m>=121.
// ---------------------------------------------------------------------------
__global__ __launch_bounds__(256) void k_prep_all(
    const float* __restrict__ w2, const float* __restrict__ w1,
    short* __restrict__ w2f, short* __restrict__ w3f, short* __restrict__ w1fB)
{
    int gid = blockIdx.x * 256 + threadIdx.x;
    if (gid < 61952) {                                   // w2f
        int idx = gid;
        int j = idx & 7, ln = (idx >> 3) & 63, tap = idx >> 9;
        int e = ln & 15, c = (ln >> 4) * 8 + j;
        float v = (e < EMB && c < INTER) ? w2[(e * INTER + c) * TLEN + tap] : 0.0f;
        w2f[idx] = (short)f2bf(v);
    } else if (gid < 78336) {                            // w3f
        int idx = gid - 61952;
        int j = idx & 7, ln = (idx >> 3) & 63, tl = (idx >> 9) & 7, ch = idx >> 12;
        int t = (ln >> 4) * 8 + j + ch * 32;
        int colIdx = (tl & 3) * 16 + (ln & 15);
        int k = colIdx + 1;
        float v = 0.0f;
        if (t < TLEN && colIdx < 60) {
            int mm = (k * t) % 121;
            float s, c2;
            sincosf(6.2831853071795864f * (float)mm / 121.0f, &s, &c2);
            v = (tl < 4) ? c2 : -s;
        }
        w3f[idx] = (short)f2bf(v);
    } else if (gid < 373248) {                           // w1fB
        int idx = gid - 78336;
        int j = idx & 7, ln = (idx >> 3) & 63;
        int rest = idx >> 9;                 // (o*8+mt)*3 + ch
        int ch = rest % 3;
        int omt = rest / 3;                  // o*8 + mt
        int mt = omt & 7, o = omt >> 3;
        int m = mt * 16 + (ln & 15);
        int c = ch * 32 + ((ln >> 4) * 8) + j;
        float v = (c < INCH && m < TLEN) ? w1[(o * INCH + c) * TLEN + m] : 0.0f;
        w1fB[idx] = (short)f2bf(v);
    }
}

// ---------------------------------------------------------------------------
// k_fused: per (b,o): MFMA D' -> in-LDS anti-diagonal prefix -> LN/tanh ->
// bf16 h3[b][o][n][i] (dedicated global buffer). 384 blocks x 256 thr.
// LDS: Dp 117128 B (stride 242 dwords: quad rows -> 2-way, free) +
//      xT 42240 B (stride 88 shorts: b-frag reads 2-way) + lnaS/lnbS.
// ---------------------------------------------------------------------------
__global__ __launch_bounds__(256, 1) void k_fused(
    const float* __restrict__ x, const short* __restrict__ w1fB,
    const float* __restrict__ b1, const float* __restrict__ lna,
    const float* __restrict__ lnb, unsigned short* __restrict__ h3g)
{
    const int blk = blockIdx.x;          // b*24 + o
    const int b = blk / INTER, o = blk - b * INTER;
    const int tid = threadIdx.x;
    const int lane = tid & 63, wid = tid >> 6;
    const int col = lane & 15, quad = lane >> 4;

    __shared__ __align__(16) float Dp[121 * 242];     // 117128 B
    __shared__ __align__(16) short xT[240 * 88];      // 42240 B (chunkbuf overlay)
    __shared__ float lnaS[TLEN], lnbS[TLEN];

    // zero xT (pad cols must be 0: bf16 garbage can be NaN; 0*NaN = NaN)
    for (int idx = tid; idx < 2640; idx += 256) ((uint4*)xT)[idx] = make_uint4(0,0,0,0);
    if (tid < TLEN) { lnaS[tid] = lna[tid]; lnbS[tid] = lnb[tid]; }
    // A-fragments for this o
    s16x8 a[8][3];
#pragma unroll
    for (int mt = 0; mt < 8; ++mt)
#pragma unroll
        for (int ch = 0; ch < 3; ++ch)
            a[mt][ch] = *(const s16x8*)(w1fB + (((o * 8 + mt) * 3 + ch) * 64 + lane) * 8);
    __syncthreads();
    // fill xT[s][c] = bf16(x[b][c][s])
    for (int idx = tid; idx < INCH * FULL; idx += 256) {
        int c = idx / FULL, s = idx - c * FULL;
        xT[s * 88 + c] = (short)f2bf(x[(b * INCH + c) * FULL + s]);
    }
    __syncthreads();

    // --- MFMA: D'[m][s'] over K = 72c (3 chunks of 32, zero-padded) ---
    for (int st = wid; st < 15; st += 4) {
        s16x8 bb[3];
#pragma unroll
        for (int ch = 0; ch < 3; ++ch) {
            int koff = ch * 32 + quad * 8;
            if (koff >= 88) koff = 0;        // k in zero-A region; any safe addr
            bb[ch] = *(const s16x8*)(xT + (st * 16 + col) * 88 + koff);
        }
#pragma unroll
        for (int mt = 0; mt < 8; ++mt) {
            f32x4 acc = {0.0f, 0.0f, 0.0f, 0.0f};
            acc = __builtin_amdgcn_mfma_f32_16x16x32_bf16(a[mt][0], bb[0], acc, 0, 0, 0);
            acc = __builtin_amdgcn_mfma_f32_16x16x32_bf16(a[mt][1], bb[1], acc, 0, 0, 0);
            acc = __builtin_amdgcn_mfma_f32_16x16x32_bf16(a[mt][2], bb[2], acc, 0, 0, 0);
#pragma unroll
            for (int r = 0; r < 4; ++r) {
                int m = mt * 16 + quad * 4 + r;
                if (m < TLEN) Dp[m * 242 + st * 16 + col] = acc[r];
            }
        }
    }
    __syncthreads();

    // --- anti-diagonal prefix: after, Dp[m][(s+m)%240] = R[m+1][s] ---
    if (tid < FULL) {
        float P = 0.0f;
        int c0 = tid;
        for (int m = 0; m < 120; m += 4) {
            int c1 = c0 + 1; c1 -= (c1 >= FULL) ? FULL : 0;
            int c2 = c1 + 1; c2 -= (c2 >= FULL) ? FULL : 0;
            int c3 = c2 + 1; c3 -= (c3 >= FULL) ? FULL : 0;
            float q0 = Dp[m * 242 + c0];
            float q1 = Dp[(m + 1) * 242 + c1];
            float q2 = Dp[(m + 2) * 242 + c2];
            float q3 = Dp[(m + 3) * 242 + c3];
            P += q0; Dp[m * 242 + c0]       = P;
            P += q1; Dp[(m + 1) * 242 + c1] = P;
            P += q2; Dp[(m + 2) * 242 + c2] = P;
            P += q3; Dp[(m + 3) * 242 + c3] = P;
            c0 = c3 + 1; c0 -= (c0 >= FULL) ? FULL : 0;
        }
        P += Dp[120 * 242 + c0];
        Dp[120 * 242 + c0] = P;
    }
    __syncthreads();

    // --- LN/tanh in two 120-row chunks; h3 staged in xT then dumped ---
    const float bias = b1[o];
    unsigned short* cb = (unsigned short*)xT;
    for (int ch2 = 0; ch2 < 2; ++ch2) {
        if (tid < 120) {
            const int n = ch2 * 120 + tid;
            int colB = n - 61; colB += (colB < 0) ? FULL : 0;
            int colC = n + 60; colC -= (colC >= FULL) ? FULL : 0;
            float s = 0.0f, s2 = 0.0f;
            int colA = n;
            for (int i = 0; i < 60; ++i) {
                float v = Dp[120 * 242 + colA] - Dp[(59 - i) * 242 + colB] + bias;
                s += v; s2 += v * v;
                ++colA; colA -= (colA >= FULL) ? FULL : 0;
            }
            { float v = Dp[120 * 242 + colC] + bias; s += v; s2 += v * v; }
            for (int i = 61; i < TLEN; ++i) {
                float v = Dp[(180 - i) * 242 + colC] + bias;
                s += v; s2 += v * v;
            }
            float mean = s * (1.0f / 121.0f);
            float var  = fmaxf((s2 - s * mean) * (1.0f / 120.0f), 0.0f);  // ddof=1
            float inv  = 1.0f / (sqrtf(var) + 1e-5f);                     // (std+eps)
            unsigned short* hrow = cb + tid * TLEN;
            colA = n;
            for (int i = 0; i < 60; ++i) {
                float v = Dp[120 * 242 + colA] - Dp[(59 - i) * 242 + colB] + bias;
                v = (v - mean) * inv * lnaS[i] + lnbS[i];
                hrow[i] = f2bf(tanhf(v));
                ++colA; colA -= (colA >= FULL) ? FULL : 0;
            }
            {
                float v = Dp[120 * 242 + colC] + bias;
                v = (v - mean) * inv * lnaS[60] + lnbS[60];
                hrow[60] = f2bf(tanhf(v));
            }
            for (int i = 61; i < TLEN; ++i) {
                float v = Dp[(180 - i) * 242 + colC] + bias;
                v = (v - mean) * inv * lnaS[i] + lnbS[i];
                hrow[i] = f2bf(tanhf(v));
            }
        }
        __syncthreads();
        uint4* dst = (uint4*)(h3g + (size_t)blk * (FULL * TLEN) + ch2 * 120 * TLEN);
        const uint4* src = (const uint4*)cb;
        for (int idx = tid; idx < 1815; idx += 256) dst[idx] = src[idx];
        __syncthreads();
    }
}

// ---------------------------------------------------------------------------
// k_enc2: per-window conv2 MFMA (ring A, 4 chains) + DFT-MFMA + parallel
// fc/bm epilogues. 3840 blocks x 256 thr.
// ---------------------------------------------------------------------------
__global__ __launch_bounds__(256) void k_enc2(
    const unsigned short* __restrict__ h3g, const short* __restrict__ w2f,
    const short* __restrict__ w3f, const float* __restrict__ b2,
    const float* __restrict__ fcw, const float* __restrict__ fcb,
    float* __restrict__ pP, float* __restrict__ pF, float* __restrict__ pA, float* __restrict__ pB,
    float* __restrict__ oLat, float* __restrict__ oP, float* __restrict__ oF,
    float* __restrict__ oA, float* __restrict__ oB)
{
    const int w   = blockIdx.x;
    const int b   = w / FULL, n = w - b * FULL;
    const int tid = threadIdx.x;
    const int lane = tid & 63, wid = tid >> 6;

    __shared__ __align__(16) short hT[248 * 40];     // 19840 B, stride 40
    __shared__ __align__(16) short hs[24 * 132];     // 6336 B
    __shared__ __align__(16) short latb[16 * 136];   // 4352 B
    __shared__ float lat[EMB * 122];                 // 3904 B
    __shared__ float S0[8], S1[8], vv[16], bm[8];

    for (int idx = tid; idx < 1240; idx += 256) ((uint4*)hT)[idx] = make_uint4(0,0,0,0);
    for (int idx = tid; idx < 272;  idx += 256) ((uint4*)latb)[idx] = make_uint4(0,0,0,0);
    if (tid < 8) { S0[tid] = 0.0f; S1[tid] = 0.0f; }

    for (int idx = tid; idx < INTER * TLEN; idx += 256) {
        int o = idx / TLEN, i = idx - o * TLEN;
        const unsigned short* h3 = h3g + (size_t)(b * INTER + o) * (FULL * TLEN) + n * TLEN;
        hs[o * 132 + i] = (short)h3[i];
    }
    __syncthreads();
    for (int idx = tid; idx < TLEN * 32; idx += 256) {
        int i = idx >> 5, o = idx & 31;
        short v = (o < INTER) ? hs[o * 132 + i] : (short)0;
        hT[(60 + i) * 40 + o] = v;
    }
    __syncthreads();

    const int m = lane & 15, quad = lane >> 4;
    const int t0 = wid * 32;

    // --- conv2 MFMA: 4 independent chains (even/odd taps x two i-tiles) ---
    f32x4 acc0a = {0,0,0,0}, acc0b = {0,0,0,0};
    f32x4 acc1a = {0,0,0,0}, acc1b = {0,0,0,0};
    const short* aptr = hT + (t0 + m) * 40 + quad * 8;
    s16x8 ring[16];
#pragma unroll
    for (int j = 0; j < 16; ++j) ring[j] = *(const s16x8*)(aptr + j * 40);

    for (int t16 = 0; t16 < 7; ++t16) {          // taps 0..111
#pragma unroll
        for (int j = 0; j < 16; j += 2) {
            const int tap = t16 * 16 + j;
            s16x8 bw0 = *(const s16x8*)(w2f + tap * 512 + lane * 8);
            s16x8 bw1 = *(const s16x8*)(w2f + (tap + 1) * 512 + lane * 8);
            s16x8 nw0 = *(const s16x8*)(aptr + (tap + 16) * 40);
            s16x8 nw1 = *(const s16x8*)(aptr + (tap + 17) * 40);
            acc0a = __builtin_amdgcn_mfma_f32_16x16x32_bf16(ring[j],     bw0, acc0a, 0, 0, 0);
            acc0b = __builtin_amdgcn_mfma_f32_16x16x32_bf16(ring[j + 1], bw1, acc0b, 0, 0, 0);
            acc1a = __builtin_amdgcn_mfma_f32_16x16x32_bf16(nw0,         bw0, acc1a, 0, 0, 0);
            acc1b = __builtin_amdgcn_mfma_f32_16x16x32_bf16(nw1,         bw1, acc1b, 0, 0, 0);
            ring[j] = nw0; ring[j + 1] = nw1;
        }
    }
#pragma unroll
    for (int j = 0; j < 8; j += 2) {             // taps 112..119
        const int tap = 112 + j;
        s16x8 bw0 = *(const s16x8*)(w2f + tap * 512 + lane * 8);
        s16x8 bw1 = *(const s16x8*)(w2f + (tap + 1) * 512 + lane * 8);
        s16x8 nw0 = *(const s16x8*)(aptr + (tap + 16) * 40);
        s16x8 nw1 = *(const s16x8*)(aptr + (tap + 17) * 40);
        acc0a = __builtin_amdgcn_mfma_f32_16x16x32_bf16(ring[j],     bw0, acc0a, 0, 0, 0);
        acc0b = __builtin_amdgcn_mfma_f32_16x16x32_bf16(ring[j + 1], bw1, acc0b, 0, 0, 0);
        acc1a = __builtin_amdgcn_mfma_f32_16x16x32_bf16(nw0,         bw0, acc1a, 0, 0, 0);
        acc1b = __builtin_amdgcn_mfma_f32_16x16x32_bf16(nw1,         bw1, acc1b, 0, 0, 0);
    }
    {                                            // tap 120
        s16x8 bw = *(const s16x8*)(w2f + 120 * 512 + lane * 8);
        s16x8 nw = *(const s16x8*)(aptr + 136 * 40);
        acc0a = __builtin_amdgcn_mfma_f32_16x16x32_bf16(ring[8], bw, acc0a, 0, 0, 0);
        acc1a = __builtin_amdgcn_mfma_f32_16x16x32_bf16(nw,      bw, acc1a, 0, 0, 0);
    }
    f32x4 acc0, acc1;
#pragma unroll
    for (int r = 0; r < 4; ++r) { acc0[r] = acc0a[r] + acc0b[r]; acc1[r] = acc1a[r] + acc1b[r]; }

    {
        const int e = lane & 15;
        if (e < EMB) {
            float bias = b2[e];
#pragma unroll
            for (int r = 0; r < 4; ++r) {
                int i0v = t0 + quad * 4 + r;
                if (i0v < TLEN) {
                    float v = acc0[r] + bias;
                    lat[e * 122 + i0v] = v;
                    latb[e * 136 + i0v] = (short)f2bf(v);
                }
                int i1v = t0 + 16 + quad * 4 + r;
                if (i1v < TLEN) {
                    float v = acc1[r] + bias;
                    lat[e * 122 + i1v] = v;
                    latb[e * 136 + i1v] = (short)f2bf(v);
                }
            }
        }
    }
    __syncthreads();

    // --- DFT via MFMA ---
    {
        f32x4 accR = {0,0,0,0};
        f32x4 accI = {0,0,0,0};
#pragma unroll
        for (int ch = 0; ch < 4; ++ch) {
            s16x8 a  = *(const s16x8*)(latb + (lane & 15) * 136 + quad * 8 + ch * 32);
            s16x8 br = *(const s16x8*)(w3f + (((ch * 8) + wid) * 64 + lane) * 8);
            s16x8 bi = *(const s16x8*)(w3f + (((ch * 8) + 4 + wid) * 64 + lane) * 8);
            accR = __builtin_amdgcn_mfma_f32_16x16x32_bf16(a, br, accR, 0, 0, 0);
            accI = __builtin_amdgcn_mfma_f32_16x16x32_bf16(a, bi, accI, 0, 0, 0);
        }
        const int colj = lane & 15;
        const int col  = wid * 16 + colj;
        const float fw = 0.5f * (float)(col + 1);
#pragma unroll
        for (int r = 0; r < 4; ++r) {
            float pw = (col < 60) ? (accR[r] * accR[r] + accI[r] * accI[r]) : 0.0f;
            float s1 = pw * fw;
#pragma unroll
            for (int off = 1; off < 16; off <<= 1) {
                pw += __shfl_xor(pw, off);
                s1 += __shfl_xor(s1, off);
            }
            if (colj == 0) {
                int e = quad * 4 + r;
                if (e < EMB) { atomicAdd(&S0[e], pw); atomicAdd(&S1[e], s1); }
            }
        }
    }
    // --- fc: 16 groups x 16 lanes, strided partials + shfl_xor reduce ---
    {
        int g = tid >> 4, l = tid & 15;
        int e_ = g >> 1, kk = g & 1;
        const float* fr = fcw + (e_ * 2 + kk) * TLEN;
        float p = 0.0f;
#pragma unroll
        for (int u = 0; u < 8; ++u) {
            int t = l + (u << 4);
            if (t < TLEN) p += lat[e_ * 122 + t] * fr[t];
        }
#pragma unroll
        for (int off = 8; off > 0; off >>= 1) p += __shfl_xor(p, off);
        if (l == 0) vv[g] = p + fcb[e_ * 2 + kk];
    }
    // --- bm: 8 groups x 32 lanes ---
    {
        int g = tid >> 5, l = tid & 31;
        float p = 0.0f;
#pragma unroll
        for (int u = 0; u < 4; ++u) {
            int t = l + (u << 5);
            if (t < TLEN) p += lat[g * 122 + t];
        }
#pragma unroll
        for (int off = 16; off > 0; off >>= 1) p += __shfl_xor(p, off);
        if (l == 0) bm[g] = p * (1.0f / 121.0f);
    }
    __syncthreads();

    if (tid < 8) {
        int e_ = tid;
        float fv = S1[e_] / S0[e_];
        float av = 2.0f * sqrtf(S0[e_]) * (1.0f / 121.0f);
        float pv = atan2f(vv[2 * e_ + 1], vv[2 * e_]) * 0.15915494309189535f;
        float bv = bm[e_];
        int gi = w * 8 + e_;
        pP[gi] = pv; pF[gi] = fv; pA[gi] = av; pB[gi] = bv;
        if (n == 0) {
            oP[b * 8 + e_] = pv;
            oF[b * 8 + e_] = fv;
            oA[b * 8 + e_] = av;
            oB[b * 8 + e_] = bv;
        }
    }
    if (n == 0) {
        for (int idx = tid; idx < EMB * TLEN; idx += 256) {
            int e_ = idx / TLEN, i = idx - e_ * TLEN;
            oLat[(b * EMB + e_) * TLEN + i] = lat[e_ * 122 + i];
        }
    }
}

// ---------------------------------------------------------------------------
// k_signal: sinusoid resynthesis + overlap-add, gather form.
// ---------------------------------------------------------------------------
__global__ __launch_bounds__(256) void k_signal(
    const float* __restrict__ pP, const float* __restrict__ pF,
    const float* __restrict__ pA, const float* __restrict__ pB,
    float* __restrict__ sig, float* __restrict__ oSig)
{
    const int blk = blockIdx.x;
    const int b = blk >> 3, e = blk & 7;
    const int tid = threadIdx.x;
    __shared__ float sp[FULL], sf[FULL], sa[FULL], sb[FULL];
    for (int nn = tid; nn < FULL; nn += 256) {
        int gi = (b * FULL + nn) * 8 + e;
        sp[nn] = pP[gi]; sf[nn] = pF[gi]; sa[nn] = pA[gi]; sb[nn] = pB[gi];
    }
    __syncthreads();
    for (int u = tid; u < LP; u += 256) {
        int nlo = (u - 120 > 0) ? (u - 120) : 0;
        int nhi = (u < 239) ? u : 239;
        float s = 0.0f;
        for (int nn = nlo; nn <= nhi; ++nn) {
            float tt = (float)(u - nn);
            float z = sf[nn] * (tt * (1.0f / 60.0f) - 1.0f) + sp[nn];
            z -= floorf(z);
            s += sa[nn] * sinf(6.2831853071795864f * z) + sb[nn];
        }
        float wgt = (u < TLEN) ? (float)(u + 1) : ((u > 239) ? (float)(LP - u) : 121.0f);
        float val = s / wgt;
        sig[(b * EMB + e) * LP + u] = val;
        if (u < TLEN) oSig[(b * EMB + e) * TLEN + u] = val;
    }
}

// ---------------------------------------------------------------------------
// k_dec1: decoder conv1. Block = (b,o), 384 x 256 thr; 4 waves x 2 channels,
// LDS partial-sum reduce; weights via block-uniform global reads.
// ---------------------------------------------------------------------------
__global__ __launch_bounds__(256) void k_dec1(
    const float* __restrict__ sig, const float* __restrict__ dw1, const float* __restrict__ db1,
    float* __restrict__ dbuf, float* __restrict__ bns)
{
    const int blk = blockIdx.x;            // b*24 + o
    const int b = blk / INTER, o = blk - b * INTER;
    const int tid = threadIdx.x;
    const int lane = tid & 63, wid = tid >> 6;
    __shared__ __align__(16) float ycp[EMB * 364];   // 11648 B
    __shared__ __align__(16) float part[4][240];     // 3840 B
    for (int idx = tid; idx < EMB * 364; idx += 256) {
        int c = idx / 364, q = idx - c * 364;
        float v = 0.0f;
        if (q >= 60 && q < 300) v = sig[(b * EMB + c) * LP + q];
        ycp[idx] = v;
    }
    __syncthreads();
    const int te = (lane < 60) ? lane : 59;
    float a0 = 0.0f, a1 = 0.0f, a2 = 0.0f, a3 = 0.0f;
    for (int cl = 0; cl < 2; ++cl) {
        const int c = wid * 2 + cl;
        const float* wr = dw1 + (o * EMB + c) * TLEN;
        const float* base = ycp + c * 364 + 4 * te;
        float4 cur = *(const float4*)base;
        for (int kb = 0; kb < 30; ++kb) {
            float4 nxt = *(const float4*)(base + 4 * kb + 4);
            float w0 = wr[4*kb], w1 = wr[4*kb+1], w2 = wr[4*kb+2], w3 = wr[4*kb+3];
            a0 += w0*cur.x; a1 += w0*cur.y; a2 += w0*cur.z; a3 += w0*cur.w;
            a0 += w1*cur.y; a1 += w1*cur.z; a2 += w1*cur.w; a3 += w1*nxt.x;
            a0 += w2*cur.z; a1 += w2*cur.w; a2 += w2*nxt.x; a3 += w2*nxt.y;
            a0 += w3*cur.w; a1 += w3*nxt.x; a2 += w3*nxt.y; a3 += w3*nxt.z;
            cur = nxt;
        }
        float wl = wr[120];
        a0 += wl*cur.x; a1 += wl*cur.y; a2 += wl*cur.z; a3 += wl*cur.w;
    }
    if (lane < 60) {
        float4* dst = (float4*)&part[wid][4 * lane];
        *dst = make_float4(a0, a1, a2, a3);
    }
    __syncthreads();
    float s = 0.0f, s2 = 0.0f;
    if (tid < 60) {
        const float bias = db1[o];
        float4 f;
        f.x = part[0][4*tid+0] + part[1][4*tid+0] + part[2][4*tid+0] + part[3][4*tid+0] + bias;
        f.y = part[0][4*tid+1] + part[1][4*tid+1] + part[2][4*tid+1] + part[3][4*tid+1] + bias;
        f.z = part[0][4*tid+2] + part[1][4*tid+2] + part[2][4*tid+2] + part[3][4*tid+2] + bias;
        f.w = part[0][4*tid+3] + part[1][4*tid+3] + part[2][4*tid+3] + part[3][4*tid+3] + bias;
        *(float4*)(dbuf + (b * INTER + o) * FULL + 4 * tid) = f;
        s  = f.x + f.y + f.z + f.w;
        s2 = f.x*f.x + f.y*f.y + f.z*f.z + f.w*f.w;
    }
    if (wid == 0) {
        for (int d = 32; d > 0; d >>= 1) { s += __shfl_down(s, d); s2 += __shfl_down(s2, d); }
        if (tid == 0) { atomicAdd(&bns[o], s); atomicAdd(&bns[24 + o], s2); }
    }
}

// ---------------------------------------------------------------------------
// k_dec2: decoder conv2 with fused BN+tanh staging. Block = (b,oc),
// 1152 x 256 thr; 4 waves x 6 channels, LDS partial-sum reduce.
// ---------------------------------------------------------------------------
__global__ __launch_bounds__(256) void k_dec2(
    const float* __restrict__ dbuf, const float* __restrict__ bns,
    const float* __restrict__ gma, const float* __restrict__ bta,
    const float* __restrict__ dw2, const float* __restrict__ db2,
    float* __restrict__ oY, float* __restrict__ oYp)
{
    const int blk = blockIdx.x;            // b*72 + oc
    const int b = blk / INCH, oc = blk - b * INCH;
    const int tid = threadIdx.x;
    const int lane = tid & 63, wid = tid >> 6;
    __shared__ __align__(16) float sdp[INTER * 364]; // 34944 B
    __shared__ __align__(16) float part[4][240];     // 3840 B
    __shared__ float scl[INTER], sft[INTER];
    if (tid < INTER) {
        float m  = bns[tid] * (1.0f / 3840.0f);
        float v  = bns[24 + tid] * (1.0f / 3840.0f) - m * m;
        float rs = rsqrtf(fmaxf(v, 0.0f) + 1e-5f);
        float g  = gma[tid];
        scl[tid] = rs * g;
        sft[tid] = bta[tid] - m * rs * g;
    }
    __syncthreads();
    for (int idx = tid; idx < INTER * 364; idx += 256) {
        int c = idx / 364, q = idx - c * 364;
        float v = 0.0f;
        if (q >= 60 && q < 300)
            v = tanhf(dbuf[(b * INTER + c) * FULL + (q - 60)] * scl[c] + sft[c]);
        sdp[idx] = v;
    }
    __syncthreads();
    const int te = (lane < 60) ? lane : 59;
    float a0 = 0.0f, a1 = 0.0f, a2 = 0.0f, a3 = 0.0f;
    for (int cl = 0; cl < 6; ++cl) {
        const int c = wid * 6 + cl;
        const float* wr = dw2 + (oc * INTER + c) * TLEN;
        const float* base = sdp + c * 364 + 4 * te;
        float4 cur = *(const float4*)base;
        for (int kb = 0; kb < 30; ++kb) {
            float4 nxt = *(const float4*)(base + 4 * kb + 4);
            float w0 = wr[4*kb], w1 = wr[4*kb+1], w2 = wr[4*kb+2], w3 = wr[4*kb+3];
            a0 += w0*cur.x; a1 += w0*cur.y; a2 += w0*cur.z; a3 += w0*cur.w;
            a0 += w1*cur.y; a1 += w1*cur.z; a2 += w1*cur.w; a3 += w1*nxt.x;
            a0 += w2*cur.z; a1 += w2*cur.w; a2 += w2*nxt.x; a3 += w2*nxt.y;
            a0 += w3*cur.w; a1 += w3*nxt.x; a2 += w3*nxt.y; a3 += w3*nxt.z;
            cur = nxt;
        }
        float wl = wr[120];
        a0 += wl*cur.x; a1 += wl*cur.y; a2 += wl*cur.z; a3 += wl*cur.w;
    }
    if (lane < 60) {
        float4* dst = (float4*)&part[wid][4 * lane];
        *dst = make_float4(a0, a1, a2, a3);
    }
    __syncthreads();
    if (tid < 60) {
        const float bias = db2[oc];
        float4 f;
        f.x = part[0][4*tid+0] + part[1][4*tid+0] + part[2][4*tid+0] + part[3][4*tid+0] + bias;
        f.y = part[0][4*tid+1] + part[1][4*tid+1] + part[2][4*tid+1] + part[3][4*tid+1] + bias;
        f.z = part[0][4*tid+2] + part[1][4*tid+2] + part[2][4*tid+2] + part[3][4*tid+2] + bias;
        f.w = part[0][4*tid+3] + part[1][4*tid+3] + part[2][4*tid+3] + part[3][4*tid+3] + bias;
        const int i = 4 * tid;
        *(float4*)(oY + (b * INCH + oc) * FULL + i) = f;
        float* yp = oYp + (b * INCH + oc) * TLEN;
        if (i     < TLEN) yp[i]     = f.x;
        if (i + 1 < TLEN) yp[i + 1] = f.y;
        if (i + 2 < TLEN) yp[i + 2] = f.z;
        if (i + 3 < TLEN) yp[i + 3] = f.w;
    }
}

// ---------------------------------------------------------------------------
extern "C" void kernel_launch(void* const* d_in, const int* in_sizes, int n_in,
                              void* d_out, int out_size, void* d_ws, size_t ws_size,
                              hipStream_t stream)
{
    const float* x   = (const float*)d_in[0];
    const float* w1  = (const float*)d_in[1];
    const float* b1  = (const float*)d_in[2];
    const float* lna = (const float*)d_in[3];
    const float* lnb = (const float*)d_in[4];
    const float* w2  = (const float*)d_in[5];
    const float* b2  = (const float*)d_in[6];
    const float* fcw = (const float*)d_in[7];
    const float* fcb = (const float*)d_in[8];
    const float* dw1 = (const float*)d_in[9];
    const float* db1 = (const float*)d_in[10];
    const float* gma = (const float*)d_in[11];
    const float* bta = (const float*)d_in[12];
    const float* dw2 = (const float*)d_in[13];
    const float* db2 = (const float*)d_in[14];

    // Output layout (flat fp32, reference return order):
    float* out  = (float*)d_out;
    float* oY   = out;                 // [16][72][240]
    float* oLat = out + 276480;        // [16][8][121]
    float* oSig = out + 291968;        // [16][8][121]
    float* oP   = out + 307456;
    float* oF   = out + 307584;
    float* oA   = out + 307712;
    float* oB   = out + 307840;
    float* oYp  = out + 307968;        // [16][72][121]

    // Workspace layout (bytes; ws_size >= 46.4 MB proven in round 6):
    //   [0, 123904)           w2f bf16 fragments [121][64][8]
    //   [123904, 156672)      w3f bf16 DFT fragments
    //   [156672, 746496)      w1fB bf16 A-fragments [24][8][3][64][8]
    //   [746496, 1422528)     fp32: pP/pF/pA/pB (dbuf overlay), sig, bns
    //   [1422528, 23725248)   h3 bf16 [16][24][240][121]
    short* w2f  = (short*)d_ws;
    short* w3f  = (short*)((char*)d_ws + 123904);
    short* w1fB = (short*)((char*)d_ws + 156672);
    float* fb   = (float*)((char*)d_ws + 746496);
    float* pP   = fb;
    float* pF   = pP + 30720;
    float* pA   = pF + 30720;
    float* pB   = pA + 30720;
    float* dbuf = fb;                  // overlay (temporally disjoint)
    float* sig  = fb + 122880;         // 46080
    float* bns  = sig + 46080;         // 48
    unsigned short* h3 = (unsigned short*)((char*)d_ws + 1422528);

    hipMemsetAsync(bns, 0, 48 * sizeof(float), stream);
    k_prep_all<<<1458, 256, 0, stream>>>(w2, w1, w2f, w3f, w1fB);
    k_fused<<<384, 256, 0, stream>>>(x, w1fB, b1, lna, lnb, h3);
    k_enc2<<<NWIN, 256, 0, stream>>>(h3, w2f, w3f, b2, fcw, fcb,
                                     pP, pF, pA, pB, oLat, oP, oF, oA, oB);
    k_signal<<<128, 256, 0, stream>>>(pP, pF, pA, pB, sig, oSig);
    k_dec1<<<384, 256, 0, stream>>>(sig, dw1, db1, dbuf, bns);
    k_dec2<<<16 * INCH, 256, 0, stream>>>(dbuf, bns, gma, bta, dw2, db2, oY, oYp);
}